// Round 9
// baseline (612.543 us; speedup 1.0000x reference)
//
#include <hip/hip_runtime.h>
#include <hip/hip_cooperative_groups.h>

namespace cg = cooperative_groups;

#define DIM 128

typedef __attribute__((ext_vector_type(2))) _Float16 half2_t;
typedef __attribute__((ext_vector_type(4))) _Float16 half4;
typedef __attribute__((ext_vector_type(8))) _Float16 half8;
typedef __attribute__((ext_vector_type(4))) float f32x4;

#define HP 136  // fp16 tile row stride (halfs): 128 + 8 pad (2-way = free)
#define UP 264  // fp16 tile row stride (halfs): 256 + 8 pad

// ------- fp32 -> fp16 conversion of all weights -------------
__global__ __launch_bounds__(256) void conv_wall(const float* __restrict__ Wk,
    const float* __restrict__ Wv, const float* __restrict__ Wo,
    const float* __restrict__ W1, const float* __restrict__ W2,
    _Float16* __restrict__ Wkh, _Float16* __restrict__ Wvh,
    _Float16* __restrict__ Woh, _Float16* __restrict__ W1h,
    _Float16* __restrict__ W2h) {
  int i = blockIdx.x * 256 + threadIdx.x;  // 114688 total
  if (i < 16384) Wkh[i] = (_Float16)Wk[i];
  else if (i < 32768) Wvh[i - 16384] = (_Float16)Wv[i - 16384];
  else if (i < 49152) Woh[i - 32768] = (_Float16)Wo[i - 32768];
  else if (i < 81920) W1h[i - 49152] = (_Float16)W1[i - 49152];
  else W2h[i - 81920] = (_Float16)W2[i - 81920];
}

// ------- cooperative CSR build: zero + hist/rank + scan + scatter ------------
__global__ __launch_bounds__(256) void csr_coop(const int* __restrict__ ei,
    int* __restrict__ cnt, int* __restrict__ rank, int* __restrict__ rs,
    int* __restrict__ bsum, int* __restrict__ esrc, float* __restrict__ stats,
    int N, int E) {
  cg::grid_group grid = cg::this_grid();
  __shared__ int sm[256];
  int t = threadIdx.x;
  int tid = blockIdx.x * 256 + t;
  int nth = gridDim.x * 256;
  int nchunk = (N + 255) / 256;

  // phase 0: zero cnt + stats
  for (int i = tid; i < N; i += nth) cnt[i] = 0;
  if (tid < 512) stats[tid] = 0.f;
  grid.sync();

  // phase 1: histogram with rank capture
  for (int e = tid; e < E; e += nth) rank[e] = atomicAdd(&cnt[ei[E + e]], 1);
  grid.sync();

  // phase 2a: per-chunk exclusive scan (block b handles chunk b)
  if (blockIdx.x < (unsigned)nchunk) {
    int i = blockIdx.x * 256 + t;
    int v = (i < N) ? cnt[i] : 0;
    sm[t] = v;
    __syncthreads();
    for (int off = 1; off < 256; off <<= 1) {
      int add = (t >= off) ? sm[t - off] : 0;
      __syncthreads();
      sm[t] += add;
      __syncthreads();
    }
    if (i < N) rs[i] = sm[t] - v;
    if (t == 255) bsum[blockIdx.x] = sm[t];
  }
  grid.sync();

  // phase 2b: scan of block sums (block 0)
  if (blockIdx.x == 0) {
    int v = (t < nchunk) ? bsum[t] : 0;
    sm[t] = v;
    __syncthreads();
    for (int off = 1; off < 256; off <<= 1) {
      int add = (t >= off) ? sm[t - off] : 0;
      __syncthreads();
      sm[t] += add;
      __syncthreads();
    }
    if (t < nchunk) bsum[t] = sm[t] - v;
  }
  grid.sync();

  // phase 2c: add block offsets
  if (blockIdx.x < (unsigned)nchunk) {
    int i = blockIdx.x * 256 + t;
    if (i < N) rs[i] += bsum[blockIdx.x];
  }
  if (tid == 0) rs[N] = E;
  grid.sync();

  // phase 3: atomic-free scatter
  for (int e = tid; e < E; e += nth) esrc[rs[ei[E + e]] + rank[e]] = ei[e];
}

// ---------------- KV projection via MFMA, interleaved KV output --------------
__global__ __launch_bounds__(256) void kv_mfma(const float* __restrict__ x,
    const _Float16* __restrict__ Wkh, const float* __restrict__ bk,
    const _Float16* __restrict__ Wvh, const float* __restrict__ bv,
    _Float16* __restrict__ KV, int N) {
  __shared__ _Float16 xs[64 * HP];  // 17.4 KB
  int tid = threadIdx.x;
  int base = blockIdx.x * 64;
  int lane = tid & 63, w = tid >> 6;
  int l15 = lane & 15, quad = lane >> 4;

  for (int i = tid; i < 64 * 32; i += 256) {
    int m = i >> 5, c4 = i & 31;
    float4 tv = ((const float4*)x)[(size_t)(base + m) * 32 + c4];
    half4 hv;
    hv.x = (_Float16)tv.x; hv.y = (_Float16)tv.y;
    hv.z = (_Float16)tv.z; hv.w = (_Float16)tv.w;
    *(half4*)&xs[m * HP + c4 * 4] = hv;
  }
  __syncthreads();

  half8 afr[4][4];
#pragma unroll
  for (int mt = 0; mt < 4; mt++)
#pragma unroll
    for (int ks = 0; ks < 4; ks++)
      afr[mt][ks] = *(const half8*)&xs[(mt * 16 + l15) * HP + ks * 32 + quad * 8];

  const _Float16* W = (w < 2) ? Wkh : Wvh;
  const float* bias = (w < 2) ? bk : bv;
  int voff = (w < 2) ? 0 : 4;
  int c0 = (w & 1) * 64;

#pragma unroll
  for (int nt = 0; nt < 4; nt++) {
    int f = c0 + nt * 16 + l15;
    half8 bfr[4];
#pragma unroll
    for (int ks = 0; ks < 4; ks++)
      bfr[ks] = *(const half8*)&W[(size_t)f * 128 + ks * 32 + quad * 8];
    f32x4 acc[4];
#pragma unroll
    for (int mt = 0; mt < 4; mt++) acc[mt] = (f32x4){0.f, 0.f, 0.f, 0.f};
#pragma unroll
    for (int ks = 0; ks < 4; ks++)
#pragma unroll
      for (int mt = 0; mt < 4; mt++)
        acc[mt] = __builtin_amdgcn_mfma_f32_16x16x32_f16(afr[mt][ks], bfr[ks],
                                                          acc[mt], 0, 0, 0);
    float bb = bias[f];
    int fo = (f >> 2) * 8 + (f & 3) + voff;  // interleaved offset
#pragma unroll
    for (int mt = 0; mt < 4; mt++)
#pragma unroll
      for (int r = 0; r < 4; r++)
        KV[(size_t)(base + mt * 16 + quad * 4 + r) * 256 + fo] =
            (_Float16)(acc[mt][r] + bb);
  }
}

// ---------------- fused attention aggregate: one wave per dst node ----------
// Interleaved KV; 2 groups x 4-deep unroll; packed fp16 math (fdot2 + pk_fma).
__global__ __launch_bounds__(256) void attn_agg(const _Float16* __restrict__ KV,
    const float* __restrict__ x, const int* __restrict__ rs,
    const int* __restrict__ esrc, _Float16* __restrict__ attn16, int N) {
  int wave = threadIdx.x >> 6, lane = threadIdx.x & 63;
  int n = blockIdx.x * 4 + wave;
  if (n >= N) return;
  int l = lane & 31, s = lane >> 5;
  float4 q = *(const float4*)&x[(size_t)n * DIM + 4 * l];
  half2_t q01 = {(_Float16)q.x, (_Float16)q.y};
  half2_t q23 = {(_Float16)q.z, (_Float16)q.w};
  int beg = rs[n], end = rs[n + 1];
  half2_t a01 = {(_Float16)0.f, (_Float16)0.f};
  half2_t a23 = a01;
  float dloc = 0.f;
  for (int e = beg + s; e < end; e += 8) {
    bool hh[4];
    int ss[4];
#pragma unroll
    for (int u = 0; u < 4; u++) hh[u] = (e + 2 * u) < end;
    ss[0] = esrc[e];
#pragma unroll
    for (int u = 1; u < 4; u++) ss[u] = hh[u] ? esrc[e + 2 * u] : ss[0];
    half8 kv[4];
#pragma unroll
    for (int u = 0; u < 4; u++)
      kv[u] = *(const half8*)&KV[(size_t)ss[u] * 256 + 8 * l];
    float p[4];
#pragma unroll
    for (int u = 0; u < 4; u++) {
      half2_t k01 = {kv[u][0], kv[u][1]};
      half2_t k23 = {kv[u][2], kv[u][3]};
      p[u] = __builtin_amdgcn_fdot2(k01, q01,
              __builtin_amdgcn_fdot2(k23, q23, 0.f, false), false);
    }
#pragma unroll
    for (int u = 0; u < 4; u++) p[u] += __shfl_xor(p[u], 1);
#pragma unroll
    for (int u = 0; u < 4; u++) p[u] += __shfl_xor(p[u], 2);
#pragma unroll
    for (int u = 0; u < 4; u++) {
      float ev = hh[u] ? __expf(p[u] * 0.25f) : 0.f;
      dloc += ev;
      _Float16 eh = (_Float16)ev;
      half2_t e2 = {eh, eh};
      half2_t v01 = {kv[u][4], kv[u][5]};
      half2_t v23 = {kv[u][6], kv[u][7]};
      a01 += e2 * v01;
      a23 += e2 * v23;
    }
  }
  float a0 = (float)a01[0], a1 = (float)a01[1];
  float a2 = (float)a23[0], a3 = (float)a23[1];
  dloc += __shfl_xor(dloc, 32);
  a0 += __shfl_xor(a0, 32);
  a1 += __shfl_xor(a1, 32);
  a2 += __shfl_xor(a2, 32);
  a3 += __shfl_xor(a3, 32);
  if (s == 0) {
    float inv = 1.0f / (dloc + 1e-16f);
    half4 o;
    o.x = (_Float16)(a0 * inv);
    o.y = (_Float16)(a1 * inv);
    o.z = (_Float16)(a2 * inv);
    o.w = (_Float16)(a3 * inv);
    *(half4*)&attn16[(size_t)n * DIM + 4 * l] = o;
  }
}

// ---------------- O-projection via MFMA + residual + BN1 stats ---------------
__global__ __launch_bounds__(256) void o_proj_mfma(const _Float16* __restrict__ attn16,
    const float* __restrict__ x, const _Float16* __restrict__ Woh,
    const float* __restrict__ bo, float* __restrict__ t,
    float* __restrict__ stats, int N) {
  __shared__ _Float16 as16[64 * HP];  // 17.4 KB
  int tid = threadIdx.x;
  int base = blockIdx.x * 64;
  int lane = tid & 63, w = tid >> 6;
  int l15 = lane & 15, quad = lane >> 4;

  for (int i = tid; i < 64 * 16; i += 256) {
    int m = i >> 4, c8 = i & 15;
    *(half8*)&as16[m * HP + c8 * 8] =
        ((const half8*)attn16)[(size_t)(base + m) * 16 + c8];
  }
  __syncthreads();

  half8 afr[4][4];
#pragma unroll
  for (int mt = 0; mt < 4; mt++)
#pragma unroll
    for (int ks = 0; ks < 4; ks++)
      afr[mt][ks] = *(const half8*)&as16[(mt * 16 + l15) * HP + ks * 32 + quad * 8];

  int c0 = w * 32;
  f32x4 acc[4][2];
#pragma unroll
  for (int mt = 0; mt < 4; mt++)
#pragma unroll
    for (int nt = 0; nt < 2; nt++) acc[mt][nt] = (f32x4){0.f, 0.f, 0.f, 0.f};
#pragma unroll
  for (int ks = 0; ks < 4; ks++) {
    half8 b[2];
#pragma unroll
    for (int nt = 0; nt < 2; nt++)
      b[nt] = *(const half8*)&Woh[(size_t)(c0 + nt * 16 + l15) * 128 + ks * 32 +
                                  quad * 8];
#pragma unroll
    for (int mt = 0; mt < 4; mt++)
#pragma unroll
      for (int nt = 0; nt < 2; nt++)
        acc[mt][nt] =
            __builtin_amdgcn_mfma_f32_16x16x32_f16(afr[mt][ks], b[nt], acc[mt][nt], 0, 0, 0);
  }

#pragma unroll
  for (int nt = 0; nt < 2; nt++) {
    int f = c0 + nt * 16 + l15;
    float bb = bo[f];
    float s = 0.f, q = 0.f;
#pragma unroll
    for (int mt = 0; mt < 4; mt++) {
#pragma unroll
      for (int r = 0; r < 4; r++) {
        int row = mt * 16 + quad * 4 + r;
        float tv = acc[mt][nt][r] + bb + x[(size_t)(base + row) * DIM + f];
        t[(size_t)(base + row) * DIM + f] = tv;
        s += tv;
        q += tv * tv;
      }
    }
    s += __shfl_xor(s, 16);
    s += __shfl_xor(s, 32);
    q += __shfl_xor(q, 16);
    q += __shfl_xor(q, 32);
    if (quad == 0) {
      atomicAdd(&stats[f], s);
      atomicAdd(&stats[128 + f], q);
    }
  }
}

// ------- fused FFN via MFMA; BN1 coef derived per-block from stats ----------
__global__ __launch_bounds__(256) void ffn_mfma(const float* __restrict__ t,
    const float* __restrict__ stats1, const float* __restrict__ g1,
    const float* __restrict__ bb1, const _Float16* __restrict__ W1h,
    const float* __restrict__ b1, const _Float16* __restrict__ W2h,
    const float* __restrict__ b2, float* __restrict__ z,
    float* __restrict__ stats2, float invN, int N) {
  __shared__ _Float16 hs[64 * HP];  // 17.4 KB
  __shared__ _Float16 us[64 * UP];  // 33.8 KB
  __shared__ float cf[256];
  int tid = threadIdx.x;
  int base = blockIdx.x * 64;
  int lane = tid & 63, w = tid >> 6;
  int l15 = lane & 15, quad = lane >> 4;

  if (tid < 128) {
    float mu = stats1[tid] * invN;
    float var = stats1[128 + tid] * invN - mu * mu;
    float a = rsqrtf(var + 1e-5f) * g1[tid];
    cf[tid] = a;
    cf[128 + tid] = bb1[tid] - mu * a;
  }
  __syncthreads();

  for (int i = tid; i < 64 * 32; i += 256) {
    int m = i >> 5, c4 = i & 31;
    float4 tv = ((const float4*)t)[(size_t)(base + m) * 32 + c4];
    float4 ca = ((const float4*)cf)[c4];
    float4 cc = ((const float4*)cf)[32 + c4];
    half4 hv;
    hv.x = (_Float16)(tv.x * ca.x + cc.x);
    hv.y = (_Float16)(tv.y * ca.y + cc.y);
    hv.z = (_Float16)(tv.z * ca.z + cc.z);
    hv.w = (_Float16)(tv.w * ca.w + cc.w);
    *(half4*)&hs[m * HP + c4 * 4] = hv;
  }
  __syncthreads();

  int n0 = w * 64;
  half8 afr[4][4];
#pragma unroll
  for (int mt = 0; mt < 4; mt++)
#pragma unroll
    for (int ks = 0; ks < 4; ks++)
      afr[mt][ks] = *(const half8*)&hs[(mt * 16 + l15) * HP + ks * 32 + quad * 8];

#pragma unroll
  for (int nt = 0; nt < 4; nt++) {
    int n = n0 + nt * 16 + l15;
    half8 bfr[4];
#pragma unroll
    for (int ks = 0; ks < 4; ks++)
      bfr[ks] = *(const half8*)&W1h[(size_t)n * 128 + ks * 32 + quad * 8];
    f32x4 acc[4];
#pragma unroll
    for (int mt = 0; mt < 4; mt++) acc[mt] = (f32x4){0.f, 0.f, 0.f, 0.f};
#pragma unroll
    for (int ks = 0; ks < 4; ks++)
#pragma unroll
      for (int mt = 0; mt < 4; mt++)
        acc[mt] = __builtin_amdgcn_mfma_f32_16x16x32_f16(afr[mt][ks], bfr[ks],
                                                          acc[mt], 0, 0, 0);
    float bias = b1[n];
#pragma unroll
    for (int mt = 0; mt < 4; mt++)
#pragma unroll
      for (int r = 0; r < 4; r++)
        us[(mt * 16 + quad * 4 + r) * UP + n] =
            (_Float16)fmaxf(acc[mt][r] + bias, 0.f);
  }
  __syncthreads();

  int n2 = w * 32;
  f32x4 acc2[4][2];
#pragma unroll
  for (int mt = 0; mt < 4; mt++)
#pragma unroll
    for (int nt = 0; nt < 2; nt++) acc2[mt][nt] = (f32x4){0.f, 0.f, 0.f, 0.f};
  for (int ks = 0; ks < 8; ks++) {
    half8 a[4], b[2];
#pragma unroll
    for (int mt = 0; mt < 4; mt++)
      a[mt] = *(const half8*)&us[(mt * 16 + l15) * UP + ks * 32 + quad * 8];
#pragma unroll
    for (int nt = 0; nt < 2; nt++)
      b[nt] = *(const half8*)&W2h[(size_t)(n2 + nt * 16 + l15) * 256 + ks * 32 +
                                  quad * 8];
#pragma unroll
    for (int mt = 0; mt < 4; mt++)
#pragma unroll
      for (int nt = 0; nt < 2; nt++)
        acc2[mt][nt] =
            __builtin_amdgcn_mfma_f32_16x16x32_f16(a[mt], b[nt], acc2[mt][nt], 0, 0, 0);
  }

#pragma unroll
  for (int nt = 0; nt < 2; nt++) {
    int f = n2 + nt * 16 + l15;
    float bz = b2[f];
    float s = 0.f, q = 0.f;
#pragma unroll
    for (int mt = 0; mt < 4; mt++) {
#pragma unroll
      for (int r = 0; r < 4; r++) {
        int row = mt * 16 + quad * 4 + r;
        float hv = (float)hs[row * HP + f];
        float zv = hv + acc2[mt][nt][r] + bz;
        z[(size_t)(base + row) * DIM + f] = zv;
        s += zv;
        q += zv * zv;
      }
    }
    s += __shfl_xor(s, 16);
    s += __shfl_xor(s, 32);
    q += __shfl_xor(q, 16);
    q += __shfl_xor(q, 32);
    if (quad == 0) {
      atomicAdd(&stats2[f], s);
      atomicAdd(&stats2[128 + f], q);
    }
  }
}

// -------- final BN2 apply; coef derived per-block from stats2 ----------------
__global__ __launch_bounds__(256) void final_apply(const float* __restrict__ z,
    const float* __restrict__ stats2, const float* __restrict__ g2,
    const float* __restrict__ bb2, float* __restrict__ out, float invN,
    int total4) {
  __shared__ float cf[256];
  int tid = threadIdx.x;
  if (tid < 128) {
    float mu = stats2[tid] * invN;
    float var = stats2[128 + tid] * invN - mu * mu;
    float a = rsqrtf(var + 1e-5f) * g2[tid];
    cf[tid] = a;
    cf[128 + tid] = bb2[tid] - mu * a;
  }
  __syncthreads();
  int i = blockIdx.x * 256 + tid;
  if (i >= total4) return;
  int f = (i * 4) & 127;
  float4 zv = ((const float4*)z)[i];
  float4 o;
  o.x = zv.x * cf[f] + cf[128 + f];
  o.y = zv.y * cf[f + 1] + cf[128 + f + 1];
  o.z = zv.z * cf[f + 2] + cf[128 + f + 2];
  o.w = zv.w * cf[f + 3] + cf[128 + f + 3];
  ((float4*)out)[i] = o;
}

extern "C" void kernel_launch(void* const* d_in, const int* in_sizes, int n_in,
                              void* d_out, int out_size, void* d_ws, size_t ws_size,
                              hipStream_t stream) {
  const float* x = (const float*)d_in[0];
  const int* ei = (const int*)d_in[1];
  const float* Wk = (const float*)d_in[2];
  const float* bk = (const float*)d_in[3];
  const float* Wv = (const float*)d_in[4];
  const float* bv = (const float*)d_in[5];
  const float* Wo = (const float*)d_in[6];
  const float* bo = (const float*)d_in[7];
  const float* bn1_g = (const float*)d_in[8];
  const float* bn1_b = (const float*)d_in[9];
  const float* W1 = (const float*)d_in[10];
  const float* b1 = (const float*)d_in[11];
  const float* W2 = (const float*)d_in[12];
  const float* b2 = (const float*)d_in[13];
  const float* bn2_g = (const float*)d_in[14];
  const float* bn2_b = (const float*)d_in[15];
  float* out = (float*)d_out;

  int N = in_sizes[0] / DIM;   // 40000 (= 625 * 64)
  int E = in_sizes[1] / 2;     // 640000

  _Float16* KV = (_Float16*)d_ws;
  _Float16* attn16 = KV + (size_t)N * 256;
  float* zbuf = (float*)(attn16 + (size_t)N * DIM);
  float* tbuf = (float*)d_ws;               // reuses KV (dead after attn_agg)
  _Float16* W1h = (_Float16*)(zbuf + (size_t)N * DIM);
  _Float16* W2h = W1h + 32768;
  _Float16* Wkh = W2h + 32768;
  _Float16* Wvh = Wkh + 16384;
  _Float16* Woh = Wvh + 16384;
  float* stats = (float*)(Woh + 16384);     // 512 floats: stats1 | stats2
  int* cnt = (int*)(stats + 512);
  int* rs = cnt + N;          // N+1
  int* rank = rs + N + 1;     // E
  int* esrc = rank + E;       // E
  int* bsum = esrc + E;       // up to 256

  float invN = 1.0f / N;

  conv_wall<<<448, 256, 0, stream>>>(Wk, Wv, Wo, W1, W2, Wkh, Wvh, Woh, W1h, W2h);
  kv_mfma<<<N / 64, 256, 0, stream>>>(x, Wkh, bk, Wvh, bv, KV, N);
  {
    void* args[] = {(void*)&ei, (void*)&cnt, (void*)&rank, (void*)&rs,
                    (void*)&bsum, (void*)&esrc, (void*)&stats, (void*)&N,
                    (void*)&E};
    hipLaunchCooperativeKernel(reinterpret_cast<void*>(csr_coop), dim3(640),
                               dim3(256), args, 0, stream);
  }
  attn_agg<<<(N + 3) / 4, 256, 0, stream>>>(KV, x, rs, esrc, attn16, N);
  o_proj_mfma<<<N / 64, 256, 0, stream>>>(attn16, x, Woh, bo, tbuf, stats, N);
  ffn_mfma<<<N / 64, 256, 0, stream>>>(tbuf, stats, bn1_g, bn1_b, W1h, b1, W2h, b2,
                                       zbuf, stats + 256, invN, N);
  final_apply<<<((N * DIM / 4) + 255) / 256, 256, 0, stream>>>(
      zbuf, stats + 256, bn2_g, bn2_b, out, invN, N * DIM / 4);
}

// Round 10
// 259.108 us; speedup vs baseline: 2.3640x; 2.3640x over previous
//
#include <hip/hip_runtime.h>

#define DIM 128

typedef __attribute__((ext_vector_type(2))) _Float16 half2_t;
typedef __attribute__((ext_vector_type(4))) _Float16 half4;
typedef __attribute__((ext_vector_type(8))) _Float16 half8;
typedef __attribute__((ext_vector_type(4))) float f32x4;

#define HP 136  // fp16 tile row stride (halfs): 128 + 8 pad (2-way = free)
#define UP 264  // fp16 tile row stride (halfs): 256 + 8 pad

// ------- fp32 -> fp16 conversion of all weights + zero cnt/stats -------------
__global__ __launch_bounds__(256) void conv_wall(const float* __restrict__ Wk,
    const float* __restrict__ Wv, const float* __restrict__ Wo,
    const float* __restrict__ W1, const float* __restrict__ W2,
    _Float16* __restrict__ Wkh, _Float16* __restrict__ Wvh,
    _Float16* __restrict__ Woh, _Float16* __restrict__ W1h,
    _Float16* __restrict__ W2h, int* __restrict__ cnt, float* __restrict__ stats,
    int N) {
  int i = blockIdx.x * 256 + threadIdx.x;  // 114688 total
  if (i < 16384) Wkh[i] = (_Float16)Wk[i];
  else if (i < 32768) Wvh[i - 16384] = (_Float16)Wv[i - 16384];
  else if (i < 49152) Woh[i - 32768] = (_Float16)Wo[i - 32768];
  else if (i < 81920) W1h[i - 49152] = (_Float16)W1[i - 49152];
  else W2h[i - 81920] = (_Float16)W2[i - 81920];
  if (i < N) cnt[i] = 0;
  if (i < 512) stats[i] = 0.f;
}

// ---------------- KV projection via MFMA, interleaved KV output --------------
__global__ __launch_bounds__(256) void kv_mfma(const float* __restrict__ x,
    const _Float16* __restrict__ Wkh, const float* __restrict__ bk,
    const _Float16* __restrict__ Wvh, const float* __restrict__ bv,
    _Float16* __restrict__ KV, int N) {
  __shared__ _Float16 xs[64 * HP];  // 17.4 KB
  int tid = threadIdx.x;
  int base = blockIdx.x * 64;
  int lane = tid & 63, w = tid >> 6;
  int l15 = lane & 15, quad = lane >> 4;

  for (int i = tid; i < 64 * 32; i += 256) {
    int m = i >> 5, c4 = i & 31;
    float4 tv = ((const float4*)x)[(size_t)(base + m) * 32 + c4];
    half4 hv;
    hv.x = (_Float16)tv.x; hv.y = (_Float16)tv.y;
    hv.z = (_Float16)tv.z; hv.w = (_Float16)tv.w;
    *(half4*)&xs[m * HP + c4 * 4] = hv;
  }
  __syncthreads();

  half8 afr[4][4];
#pragma unroll
  for (int mt = 0; mt < 4; mt++)
#pragma unroll
    for (int ks = 0; ks < 4; ks++)
      afr[mt][ks] = *(const half8*)&xs[(mt * 16 + l15) * HP + ks * 32 + quad * 8];

  const _Float16* W = (w < 2) ? Wkh : Wvh;
  const float* bias = (w < 2) ? bk : bv;
  int voff = (w < 2) ? 0 : 4;
  int c0 = (w & 1) * 64;

#pragma unroll
  for (int nt = 0; nt < 4; nt++) {
    int f = c0 + nt * 16 + l15;
    half8 bfr[4];
#pragma unroll
    for (int ks = 0; ks < 4; ks++)
      bfr[ks] = *(const half8*)&W[(size_t)f * 128 + ks * 32 + quad * 8];
    f32x4 acc[4];
#pragma unroll
    for (int mt = 0; mt < 4; mt++) acc[mt] = (f32x4){0.f, 0.f, 0.f, 0.f};
#pragma unroll
    for (int ks = 0; ks < 4; ks++)
#pragma unroll
      for (int mt = 0; mt < 4; mt++)
        acc[mt] = __builtin_amdgcn_mfma_f32_16x16x32_f16(afr[mt][ks], bfr[ks],
                                                          acc[mt], 0, 0, 0);
    float bb = bias[f];
    int fo = (f >> 2) * 8 + (f & 3) + voff;  // interleaved offset
#pragma unroll
    for (int mt = 0; mt < 4; mt++)
#pragma unroll
      for (int r = 0; r < 4; r++)
        KV[(size_t)(base + mt * 16 + quad * 4 + r) * 256 + fo] =
            (_Float16)(acc[mt][r] + bb);
  }
}

// ---------------- CSR build: hist with rank capture ----------------
__global__ __launch_bounds__(256) void hist_rank(const int* __restrict__ ei,
    int* __restrict__ cnt, int* __restrict__ rank, int E) {
  int e = blockIdx.x * 256 + threadIdx.x;
  if (e < E) rank[e] = atomicAdd(&cnt[ei[E + e]], 1);
}

__global__ __launch_bounds__(256) void scanA(const int* __restrict__ cnt,
    int* __restrict__ rs, int* __restrict__ bsum, int N) {
  __shared__ int s[256];
  int t = threadIdx.x;
  int i = blockIdx.x * 256 + t;
  int v = (i < N) ? cnt[i] : 0;
  s[t] = v;
  __syncthreads();
  for (int off = 1; off < 256; off <<= 1) {
    int add = (t >= off) ? s[t - off] : 0;
    __syncthreads();
    s[t] += add;
    __syncthreads();
  }
  if (i < N) rs[i] = s[t] - v;
  if (t == 255) bsum[blockIdx.x] = s[t];
}

__global__ __launch_bounds__(256) void scanB(int* __restrict__ bsum, int nb) {
  __shared__ int s[256];
  int t = threadIdx.x;
  int v = (t < nb) ? bsum[t] : 0;
  s[t] = v;
  __syncthreads();
  for (int off = 1; off < 256; off <<= 1) {
    int add = (t >= off) ? s[t - off] : 0;
    __syncthreads();
    s[t] += add;
    __syncthreads();
  }
  if (t < nb) bsum[t] = s[t] - v;
}

__global__ __launch_bounds__(256) void scanC(int* __restrict__ rs,
    const int* __restrict__ bsum, int N, int E) {
  int i = blockIdx.x * 256 + threadIdx.x;
  if (i < N) rs[i] += bsum[blockIdx.x];
  if (i == 0) rs[N] = E;
}

// ---------------- atomic-free scatter ----------------
__global__ __launch_bounds__(256) void scatter2(const int* __restrict__ ei,
    const int* __restrict__ rs, const int* __restrict__ rank,
    int* __restrict__ esrc, int E) {
  int e = blockIdx.x * 256 + threadIdx.x;
  if (e < E) esrc[rs[ei[E + e]] + rank[e]] = ei[e];
}

// ---------------- fused attention aggregate: one wave per dst node ----------
// Interleaved KV; 2 groups x 4-deep unroll; packed fp16 math (fdot2 + pk_fma).
__global__ __launch_bounds__(256) void attn_agg(const _Float16* __restrict__ KV,
    const float* __restrict__ x, const int* __restrict__ rs,
    const int* __restrict__ esrc, _Float16* __restrict__ attn16, int N) {
  int wave = threadIdx.x >> 6, lane = threadIdx.x & 63;
  int n = blockIdx.x * 4 + wave;
  if (n >= N) return;
  int l = lane & 31, s = lane >> 5;
  float4 q = *(const float4*)&x[(size_t)n * DIM + 4 * l];
  half2_t q01 = {(_Float16)q.x, (_Float16)q.y};
  half2_t q23 = {(_Float16)q.z, (_Float16)q.w};
  int beg = rs[n], end = rs[n + 1];
  half2_t a01 = {(_Float16)0.f, (_Float16)0.f};
  half2_t a23 = a01;
  float dloc = 0.f;
  for (int e = beg + s; e < end; e += 8) {
    bool hh[4];
    int ss[4];
#pragma unroll
    for (int u = 0; u < 4; u++) hh[u] = (e + 2 * u) < end;
    ss[0] = esrc[e];
#pragma unroll
    for (int u = 1; u < 4; u++) ss[u] = hh[u] ? esrc[e + 2 * u] : ss[0];
    half8 kv[4];
#pragma unroll
    for (int u = 0; u < 4; u++)
      kv[u] = *(const half8*)&KV[(size_t)ss[u] * 256 + 8 * l];
    float p[4];
#pragma unroll
    for (int u = 0; u < 4; u++) {
      half2_t k01 = {kv[u][0], kv[u][1]};
      half2_t k23 = {kv[u][2], kv[u][3]};
      p[u] = __builtin_amdgcn_fdot2(k01, q01,
              __builtin_amdgcn_fdot2(k23, q23, 0.f, false), false);
    }
#pragma unroll
    for (int u = 0; u < 4; u++) p[u] += __shfl_xor(p[u], 1);
#pragma unroll
    for (int u = 0; u < 4; u++) p[u] += __shfl_xor(p[u], 2);
#pragma unroll
    for (int u = 0; u < 4; u++) {
      float ev = hh[u] ? __expf(p[u] * 0.25f) : 0.f;
      dloc += ev;
      _Float16 eh = (_Float16)ev;
      half2_t e2 = {eh, eh};
      half2_t v01 = {kv[u][4], kv[u][5]};
      half2_t v23 = {kv[u][6], kv[u][7]};
      a01 += e2 * v01;
      a23 += e2 * v23;
    }
  }
  float a0 = (float)a01[0], a1 = (float)a01[1];
  float a2 = (float)a23[0], a3 = (float)a23[1];
  dloc += __shfl_xor(dloc, 32);
  a0 += __shfl_xor(a0, 32);
  a1 += __shfl_xor(a1, 32);
  a2 += __shfl_xor(a2, 32);
  a3 += __shfl_xor(a3, 32);
  if (s == 0) {
    float inv = 1.0f / (dloc + 1e-16f);
    half4 o;
    o.x = (_Float16)(a0 * inv);
    o.y = (_Float16)(a1 * inv);
    o.z = (_Float16)(a2 * inv);
    o.w = (_Float16)(a3 * inv);
    *(half4*)&attn16[(size_t)n * DIM + 4 * l] = o;
  }
}

// ---------------- O-projection via MFMA + residual + BN1 stats ---------------
__global__ __launch_bounds__(256) void o_proj_mfma(const _Float16* __restrict__ attn16,
    const float* __restrict__ x, const _Float16* __restrict__ Woh,
    const float* __restrict__ bo, float* __restrict__ t,
    float* __restrict__ stats, int N) {
  __shared__ _Float16 as16[64 * HP];  // 17.4 KB
  int tid = threadIdx.x;
  int base = blockIdx.x * 64;
  int lane = tid & 63, w = tid >> 6;
  int l15 = lane & 15, quad = lane >> 4;

  for (int i = tid; i < 64 * 16; i += 256) {
    int m = i >> 4, c8 = i & 15;
    *(half8*)&as16[m * HP + c8 * 8] =
        ((const half8*)attn16)[(size_t)(base + m) * 16 + c8];
  }
  __syncthreads();

  half8 afr[4][4];
#pragma unroll
  for (int mt = 0; mt < 4; mt++)
#pragma unroll
    for (int ks = 0; ks < 4; ks++)
      afr[mt][ks] = *(const half8*)&as16[(mt * 16 + l15) * HP + ks * 32 + quad * 8];

  int c0 = w * 32;
  f32x4 acc[4][2];
#pragma unroll
  for (int mt = 0; mt < 4; mt++)
#pragma unroll
    for (int nt = 0; nt < 2; nt++) acc[mt][nt] = (f32x4){0.f, 0.f, 0.f, 0.f};
#pragma unroll
  for (int ks = 0; ks < 4; ks++) {
    half8 b[2];
#pragma unroll
    for (int nt = 0; nt < 2; nt++)
      b[nt] = *(const half8*)&Woh[(size_t)(c0 + nt * 16 + l15) * 128 + ks * 32 +
                                  quad * 8];
#pragma unroll
    for (int mt = 0; mt < 4; mt++)
#pragma unroll
      for (int nt = 0; nt < 2; nt++)
        acc[mt][nt] =
            __builtin_amdgcn_mfma_f32_16x16x32_f16(afr[mt][ks], b[nt], acc[mt][nt], 0, 0, 0);
  }

#pragma unroll
  for (int nt = 0; nt < 2; nt++) {
    int f = c0 + nt * 16 + l15;
    float bb = bo[f];
    float s = 0.f, q = 0.f;
#pragma unroll
    for (int mt = 0; mt < 4; mt++) {
#pragma unroll
      for (int r = 0; r < 4; r++) {
        int row = mt * 16 + quad * 4 + r;
        float tv = acc[mt][nt][r] + bb + x[(size_t)(base + row) * DIM + f];
        t[(size_t)(base + row) * DIM + f] = tv;
        s += tv;
        q += tv * tv;
      }
    }
    s += __shfl_xor(s, 16);
    s += __shfl_xor(s, 32);
    q += __shfl_xor(q, 16);
    q += __shfl_xor(q, 32);
    if (quad == 0) {
      atomicAdd(&stats[f], s);
      atomicAdd(&stats[128 + f], q);
    }
  }
}

// ------- fused FFN via MFMA; BN1 coef derived per-block from stats ----------
__global__ __launch_bounds__(256) void ffn_mfma(const float* __restrict__ t,
    const float* __restrict__ stats1, const float* __restrict__ g1,
    const float* __restrict__ bb1, const _Float16* __restrict__ W1h,
    const float* __restrict__ b1, const _Float16* __restrict__ W2h,
    const float* __restrict__ b2, float* __restrict__ z,
    float* __restrict__ stats2, float invN, int N) {
  __shared__ _Float16 hs[64 * HP];  // 17.4 KB
  __shared__ _Float16 us[64 * UP];  // 33.8 KB
  __shared__ float cf[256];
  int tid = threadIdx.x;
  int base = blockIdx.x * 64;
  int lane = tid & 63, w = tid >> 6;
  int l15 = lane & 15, quad = lane >> 4;

  if (tid < 128) {
    float mu = stats1[tid] * invN;
    float var = stats1[128 + tid] * invN - mu * mu;
    float a = rsqrtf(var + 1e-5f) * g1[tid];
    cf[tid] = a;
    cf[128 + tid] = bb1[tid] - mu * a;
  }
  __syncthreads();

  for (int i = tid; i < 64 * 32; i += 256) {
    int m = i >> 5, c4 = i & 31;
    float4 tv = ((const float4*)t)[(size_t)(base + m) * 32 + c4];
    float4 ca = ((const float4*)cf)[c4];
    float4 cc = ((const float4*)cf)[32 + c4];
    half4 hv;
    hv.x = (_Float16)(tv.x * ca.x + cc.x);
    hv.y = (_Float16)(tv.y * ca.y + cc.y);
    hv.z = (_Float16)(tv.z * ca.z + cc.z);
    hv.w = (_Float16)(tv.w * ca.w + cc.w);
    *(half4*)&hs[m * HP + c4 * 4] = hv;
  }
  __syncthreads();

  int n0 = w * 64;
  half8 afr[4][4];
#pragma unroll
  for (int mt = 0; mt < 4; mt++)
#pragma unroll
    for (int ks = 0; ks < 4; ks++)
      afr[mt][ks] = *(const half8*)&hs[(mt * 16 + l15) * HP + ks * 32 + quad * 8];

#pragma unroll
  for (int nt = 0; nt < 4; nt++) {
    int n = n0 + nt * 16 + l15;
    half8 bfr[4];
#pragma unroll
    for (int ks = 0; ks < 4; ks++)
      bfr[ks] = *(const half8*)&W1h[(size_t)n * 128 + ks * 32 + quad * 8];
    f32x4 acc[4];
#pragma unroll
    for (int mt = 0; mt < 4; mt++) acc[mt] = (f32x4){0.f, 0.f, 0.f, 0.f};
#pragma unroll
    for (int ks = 0; ks < 4; ks++)
#pragma unroll
      for (int mt = 0; mt < 4; mt++)
        acc[mt] = __builtin_amdgcn_mfma_f32_16x16x32_f16(afr[mt][ks], bfr[ks],
                                                          acc[mt], 0, 0, 0);
    float bias = b1[n];
#pragma unroll
    for (int mt = 0; mt < 4; mt++)
#pragma unroll
      for (int r = 0; r < 4; r++)
        us[(mt * 16 + quad * 4 + r) * UP + n] =
            (_Float16)fmaxf(acc[mt][r] + bias, 0.f);
  }
  __syncthreads();

  int n2 = w * 32;
  f32x4 acc2[4][2];
#pragma unroll
  for (int mt = 0; mt < 4; mt++)
#pragma unroll
    for (int nt = 0; nt < 2; nt++) acc2[mt][nt] = (f32x4){0.f, 0.f, 0.f, 0.f};
  for (int ks = 0; ks < 8; ks++) {
    half8 a[4], b[2];
#pragma unroll
    for (int mt = 0; mt < 4; mt++)
      a[mt] = *(const half8*)&us[(mt * 16 + l15) * UP + ks * 32 + quad * 8];
#pragma unroll
    for (int nt = 0; nt < 2; nt++)
      b[nt] = *(const half8*)&W2h[(size_t)(n2 + nt * 16 + l15) * 256 + ks * 32 +
                                  quad * 8];
#pragma unroll
    for (int mt = 0; mt < 4; mt++)
#pragma unroll
      for (int nt = 0; nt < 2; nt++)
        acc2[mt][nt] =
            __builtin_amdgcn_mfma_f32_16x16x32_f16(a[mt], b[nt], acc2[mt][nt], 0, 0, 0);
  }

#pragma unroll
  for (int nt = 0; nt < 2; nt++) {
    int f = n2 + nt * 16 + l15;
    float bz = b2[f];
    float s = 0.f, q = 0.f;
#pragma unroll
    for (int mt = 0; mt < 4; mt++) {
#pragma unroll
      for (int r = 0; r < 4; r++) {
        int row = mt * 16 + quad * 4 + r;
        float hv = (float)hs[row * HP + f];
        float zv = hv + acc2[mt][nt][r] + bz;
        z[(size_t)(base + row) * DIM + f] = zv;
        s += zv;
        q += zv * zv;
      }
    }
    s += __shfl_xor(s, 16);
    s += __shfl_xor(s, 32);
    q += __shfl_xor(q, 16);
    q += __shfl_xor(q, 32);
    if (quad == 0) {
      atomicAdd(&stats2[f], s);
      atomicAdd(&stats2[128 + f], q);
    }
  }
}

// -------- final BN2 apply; coef derived per-block from stats2 ----------------
__global__ __launch_bounds__(256) void final_apply(const float* __restrict__ z,
    const float* __restrict__ stats2, const float* __restrict__ g2,
    const float* __restrict__ bb2, float* __restrict__ out, float invN,
    int total4) {
  __shared__ float cf[256];
  int tid = threadIdx.x;
  if (tid < 128) {
    float mu = stats2[tid] * invN;
    float var = stats2[128 + tid] * invN - mu * mu;
    float a = rsqrtf(var + 1e-5f) * g2[tid];
    cf[tid] = a;
    cf[128 + tid] = bb2[tid] - mu * a;
  }
  __syncthreads();
  int i = blockIdx.x * 256 + tid;
  if (i >= total4) return;
  int f = (i * 4) & 127;
  float4 zv = ((const float4*)z)[i];
  float4 o;
  o.x = zv.x * cf[f] + cf[128 + f];
  o.y = zv.y * cf[f + 1] + cf[128 + f + 1];
  o.z = zv.z * cf[f + 2] + cf[128 + f + 2];
  o.w = zv.w * cf[f + 3] + cf[128 + f + 3];
  ((float4*)out)[i] = o;
}

extern "C" void kernel_launch(void* const* d_in, const int* in_sizes, int n_in,
                              void* d_out, int out_size, void* d_ws, size_t ws_size,
                              hipStream_t stream) {
  const float* x = (const float*)d_in[0];
  const int* ei = (const int*)d_in[1];
  const float* Wk = (const float*)d_in[2];
  const float* bk = (const float*)d_in[3];
  const float* Wv = (const float*)d_in[4];
  const float* bv = (const float*)d_in[5];
  const float* Wo = (const float*)d_in[6];
  const float* bo = (const float*)d_in[7];
  const float* bn1_g = (const float*)d_in[8];
  const float* bn1_b = (const float*)d_in[9];
  const float* W1 = (const float*)d_in[10];
  const float* b1 = (const float*)d_in[11];
  const float* W2 = (const float*)d_in[12];
  const float* b2 = (const float*)d_in[13];
  const float* bn2_g = (const float*)d_in[14];
  const float* bn2_b = (const float*)d_in[15];
  float* out = (float*)d_out;

  int N = in_sizes[0] / DIM;   // 40000 (= 625 * 64)
  int E = in_sizes[1] / 2;     // 640000

  _Float16* KV = (_Float16*)d_ws;
  _Float16* attn16 = KV + (size_t)N * 256;
  float* zbuf = (float*)(attn16 + (size_t)N * DIM);
  float* tbuf = (float*)d_ws;               // reuses KV (dead after attn_agg)
  _Float16* W1h = (_Float16*)(zbuf + (size_t)N * DIM);
  _Float16* W2h = W1h + 32768;
  _Float16* Wkh = W2h + 32768;
  _Float16* Wvh = Wkh + 16384;
  _Float16* Woh = Wvh + 16384;
  float* stats = (float*)(Woh + 16384);     // 512 floats: stats1 | stats2
  int* cnt = (int*)(stats + 512);
  int* rs = cnt + N;          // N+1
  int* rank = rs + N + 1;     // E
  int* esrc = rank + E;       // E
  int* bsum = esrc + E;       // up to 256

  int nblk = (N + 255) / 256;
  float invN = 1.0f / N;

  conv_wall<<<448, 256, 0, stream>>>(Wk, Wv, Wo, W1, W2, Wkh, Wvh, Woh, W1h, W2h,
                                     cnt, stats, N);
  kv_mfma<<<N / 64, 256, 0, stream>>>(x, Wkh, bk, Wvh, bv, KV, N);
  hist_rank<<<(E + 255) / 256, 256, 0, stream>>>(ei, cnt, rank, E);
  scanA<<<nblk, 256, 0, stream>>>(cnt, rs, bsum, N);
  scanB<<<1, 256, 0, stream>>>(bsum, nblk);
  scanC<<<nblk, 256, 0, stream>>>(rs, bsum, N, E);
  scatter2<<<(E + 255) / 256, 256, 0, stream>>>(ei, rs, rank, esrc, E);
  attn_agg<<<(N + 3) / 4, 256, 0, stream>>>(KV, x, rs, esrc, attn16, N);
  o_proj_mfma<<<N / 64, 256, 0, stream>>>(attn16, x, Woh, bo, tbuf, stats, N);
  ffn_mfma<<<N / 64, 256, 0, stream>>>(tbuf, stats, bn1_g, bn1_b, W1h, b1, W2h, b2,
                                       zbuf, stats + 256, invN, N);
  final_apply<<<((N * DIM / 4) + 255) / 256, 256, 0, stream>>>(
      zbuf, stats + 256, bn2_g, bn2_b, out, invN, N * DIM / 4);
}

// Round 11
// 251.300 us; speedup vs baseline: 2.4375x; 1.0311x over previous
//
#include <hip/hip_runtime.h>

#define DIM 128
#define NSHARD 8

typedef __attribute__((ext_vector_type(2))) float f32x2;
typedef __attribute__((ext_vector_type(4))) _Float16 half4;
typedef __attribute__((ext_vector_type(8))) _Float16 half8;
typedef __attribute__((ext_vector_type(4))) float f32x4;

#define HP 136  // fp16 tile row stride (halfs): 128 + 8 pad (2-way = free)
#define UP 264  // fp16 tile row stride (halfs): 256 + 8 pad

__device__ __forceinline__ unsigned char to_fp8(float v) {
  return (unsigned char)(__builtin_amdgcn_cvt_pk_fp8_f32(v, v, 0, false) & 0xff);
}

// ------- fp32 -> fp16 conversion of all weights + zero cnt/stats -------------
__global__ __launch_bounds__(256) void conv_wall(const float* __restrict__ Wk,
    const float* __restrict__ Wv, const float* __restrict__ Wo,
    const float* __restrict__ W1, const float* __restrict__ W2,
    _Float16* __restrict__ Wkh, _Float16* __restrict__ Wvh,
    _Float16* __restrict__ Woh, _Float16* __restrict__ W1h,
    _Float16* __restrict__ W2h, int* __restrict__ cnt, float* __restrict__ stats,
    int N) {
  int i = blockIdx.x * 256 + threadIdx.x;
  int nth = gridDim.x * 256;
  if (i < 16384) Wkh[i] = (_Float16)Wk[i];
  else if (i < 32768) Wvh[i - 16384] = (_Float16)Wv[i - 16384];
  else if (i < 49152) Woh[i - 32768] = (_Float16)Wo[i - 32768];
  else if (i < 81920) W1h[i - 49152] = (_Float16)W1[i - 49152];
  else if (i < 114688) W2h[i - 81920] = (_Float16)W2[i - 81920];
  for (int j = i; j < N * NSHARD; j += nth) cnt[j] = 0;
  if (i < 512) stats[i] = 0.f;
}

// ------------- KV projection via MFMA, interleaved fp8 KV output -------------
// KV8 row (256 B/node): chunk g = [K[4g..4g+3] | V[4g..4g+3]] (8 fp8 bytes).
__global__ __launch_bounds__(256) void kv_mfma(const float* __restrict__ x,
    const _Float16* __restrict__ Wkh, const float* __restrict__ bk,
    const _Float16* __restrict__ Wvh, const float* __restrict__ bv,
    unsigned char* __restrict__ KV8, int N) {
  __shared__ _Float16 xs[64 * HP];  // 17.4 KB
  int tid = threadIdx.x;
  int base = blockIdx.x * 64;
  int lane = tid & 63, w = tid >> 6;
  int l15 = lane & 15, quad = lane >> 4;

  for (int i = tid; i < 64 * 32; i += 256) {
    int m = i >> 5, c4 = i & 31;
    float4 tv = ((const float4*)x)[(size_t)(base + m) * 32 + c4];
    half4 hv;
    hv.x = (_Float16)tv.x; hv.y = (_Float16)tv.y;
    hv.z = (_Float16)tv.z; hv.w = (_Float16)tv.w;
    *(half4*)&xs[m * HP + c4 * 4] = hv;
  }
  __syncthreads();

  half8 afr[4][4];
#pragma unroll
  for (int mt = 0; mt < 4; mt++)
#pragma unroll
    for (int ks = 0; ks < 4; ks++)
      afr[mt][ks] = *(const half8*)&xs[(mt * 16 + l15) * HP + ks * 32 + quad * 8];

  const _Float16* W = (w < 2) ? Wkh : Wvh;
  const float* bias = (w < 2) ? bk : bv;
  int voff = (w < 2) ? 0 : 4;
  int c0 = (w & 1) * 64;

#pragma unroll
  for (int nt = 0; nt < 4; nt++) {
    int f = c0 + nt * 16 + l15;
    half8 bfr[4];
#pragma unroll
    for (int ks = 0; ks < 4; ks++)
      bfr[ks] = *(const half8*)&W[(size_t)f * 128 + ks * 32 + quad * 8];
    f32x4 acc[4];
#pragma unroll
    for (int mt = 0; mt < 4; mt++) acc[mt] = (f32x4){0.f, 0.f, 0.f, 0.f};
#pragma unroll
    for (int ks = 0; ks < 4; ks++)
#pragma unroll
      for (int mt = 0; mt < 4; mt++)
        acc[mt] = __builtin_amdgcn_mfma_f32_16x16x32_f16(afr[mt][ks], bfr[ks],
                                                          acc[mt], 0, 0, 0);
    float bb = bias[f];
    int fo = (f >> 2) * 8 + (f & 3) + voff;  // interleaved byte offset
#pragma unroll
    for (int mt = 0; mt < 4; mt++)
#pragma unroll
      for (int r = 0; r < 4; r++)
        KV8[(size_t)(base + mt * 16 + quad * 4 + r) * 256 + fo] =
            to_fp8(acc[mt][r] + bb);
  }
}

// ---------- CSR build: hist with rank capture, counters sharded x8 ----------
__global__ __launch_bounds__(256) void hist_rank(const int* __restrict__ ei,
    int* __restrict__ cnt, int* __restrict__ rank, int N, int E) {
  int e = blockIdx.x * 256 + threadIdx.x;
  if (e < E) rank[e] = atomicAdd(&cnt[(e & (NSHARD - 1)) * N + ei[E + e]], 1);
}

__global__ __launch_bounds__(256) void scanA(const int* __restrict__ cnt,
    int* __restrict__ rs, int* __restrict__ bsum, int N) {
  __shared__ int s[256];
  int t = threadIdx.x;
  int i = blockIdx.x * 256 + t;
  int v = 0;
  if (i < N)
#pragma unroll
    for (int sh = 0; sh < NSHARD; sh++) v += cnt[sh * N + i];
  s[t] = v;
  __syncthreads();
  for (int off = 1; off < 256; off <<= 1) {
    int add = (t >= off) ? s[t - off] : 0;
    __syncthreads();
    s[t] += add;
    __syncthreads();
  }
  if (i < N) rs[i] = s[t] - v;
  if (t == 255) bsum[blockIdx.x] = s[t];
}

__global__ __launch_bounds__(256) void scanB(int* __restrict__ bsum, int nb) {
  __shared__ int s[256];
  int t = threadIdx.x;
  int v = (t < nb) ? bsum[t] : 0;
  s[t] = v;
  __syncthreads();
  for (int off = 1; off < 256; off <<= 1) {
    int add = (t >= off) ? s[t - off] : 0;
    __syncthreads();
    s[t] += add;
    __syncthreads();
  }
  if (t < nb) bsum[t] = s[t] - v;
}

// adds block offsets to rs and emits per-shard bases
__global__ __launch_bounds__(256) void scanC(int* __restrict__ rs,
    const int* __restrict__ bsum, const int* __restrict__ cnt,
    int* __restrict__ rs_shard, int N, int E) {
  int i = blockIdx.x * 256 + threadIdx.x;
  if (i < N) {
    int b = rs[i] + bsum[blockIdx.x];
    rs[i] = b;
#pragma unroll
    for (int sh = 0; sh < NSHARD; sh++) {
      rs_shard[sh * N + i] = b;
      b += cnt[sh * N + i];
    }
  }
  if (i == 0) rs[N] = E;
}

// ---------------- atomic-free scatter ----------------
__global__ __launch_bounds__(256) void scatter2(const int* __restrict__ ei,
    const int* __restrict__ rs_shard, const int* __restrict__ rank,
    int* __restrict__ esrc, int N, int E) {
  int e = blockIdx.x * 256 + threadIdx.x;
  if (e < E)
    esrc[rs_shard[(e & (NSHARD - 1)) * N + ei[E + e]] + rank[e]] = ei[e];
}

// ---------------- fused attention aggregate: one wave per dst node ----------
// fp8 interleaved KV: one dwordx2/lane per edge = K4+V4. 2 groups x 4 unroll.
__global__ __launch_bounds__(256) void attn_agg(const unsigned char* __restrict__ KV8,
    const float* __restrict__ x, const int* __restrict__ rs,
    const int* __restrict__ esrc, _Float16* __restrict__ attn16, int N) {
  int wave = threadIdx.x >> 6, lane = threadIdx.x & 63;
  int n = blockIdx.x * 4 + wave;
  if (n >= N) return;
  int l = lane & 31, s = lane >> 5;
  float4 q = *(const float4*)&x[(size_t)n * DIM + 4 * l];
  int beg = rs[n], end = rs[n + 1];
  float a0 = 0.f, a1 = 0.f, a2 = 0.f, a3 = 0.f, dloc = 0.f;
  for (int e = beg + s; e < end; e += 8) {
    bool hh[4];
    int ss[4];
#pragma unroll
    for (int u = 0; u < 4; u++) hh[u] = (e + 2 * u) < end;
    ss[0] = esrc[e];
#pragma unroll
    for (int u = 1; u < 4; u++) ss[u] = hh[u] ? esrc[e + 2 * u] : ss[0];
    uint2 kv[4];
#pragma unroll
    for (int u = 0; u < 4; u++)
      kv[u] = *(const uint2*)&KV8[(size_t)ss[u] * 256 + 8 * l];
    float p[4];
#pragma unroll
    for (int u = 0; u < 4; u++) {
      f32x2 k01 = __builtin_amdgcn_cvt_pk_f32_fp8(kv[u].x, false);
      f32x2 k23 = __builtin_amdgcn_cvt_pk_f32_fp8(kv[u].x, true);
      p[u] = k01[0] * q.x + k01[1] * q.y + k23[0] * q.z + k23[1] * q.w;
    }
#pragma unroll
    for (int u = 0; u < 4; u++) p[u] += __shfl_xor(p[u], 1);
#pragma unroll
    for (int u = 0; u < 4; u++) p[u] += __shfl_xor(p[u], 2);
#pragma unroll
    for (int u = 0; u < 4; u++) {
      float ev = hh[u] ? __expf(p[u] * 0.25f) : 0.f;
      dloc += ev;
      f32x2 v01 = __builtin_amdgcn_cvt_pk_f32_fp8(kv[u].y, false);
      f32x2 v23 = __builtin_amdgcn_cvt_pk_f32_fp8(kv[u].y, true);
      a0 += ev * v01[0];
      a1 += ev * v01[1];
      a2 += ev * v23[0];
      a3 += ev * v23[1];
    }
  }
  dloc += __shfl_xor(dloc, 32);
  a0 += __shfl_xor(a0, 32);
  a1 += __shfl_xor(a1, 32);
  a2 += __shfl_xor(a2, 32);
  a3 += __shfl_xor(a3, 32);
  if (s == 0) {
    float inv = 1.0f / (dloc + 1e-16f);
    half4 o;
    o.x = (_Float16)(a0 * inv);
    o.y = (_Float16)(a1 * inv);
    o.z = (_Float16)(a2 * inv);
    o.w = (_Float16)(a3 * inv);
    *(half4*)&attn16[(size_t)n * DIM + 4 * l] = o;
  }
}

// ---------------- O-projection via MFMA + residual + BN1 stats ---------------
__global__ __launch_bounds__(256) void o_proj_mfma(const _Float16* __restrict__ attn16,
    const float* __restrict__ x, const _Float16* __restrict__ Woh,
    const float* __restrict__ bo, float* __restrict__ t,
    float* __restrict__ stats, int N) {
  __shared__ _Float16 as16[64 * HP];  // 17.4 KB
  int tid = threadIdx.x;
  int base = blockIdx.x * 64;
  int lane = tid & 63, w = tid >> 6;
  int l15 = lane & 15, quad = lane >> 4;

  for (int i = tid; i < 64 * 16; i += 256) {
    int m = i >> 4, c8 = i & 15;
    *(half8*)&as16[m * HP + c8 * 8] =
        ((const half8*)attn16)[(size_t)(base + m) * 16 + c8];
  }
  __syncthreads();

  half8 afr[4][4];
#pragma unroll
  for (int mt = 0; mt < 4; mt++)
#pragma unroll
    for (int ks = 0; ks < 4; ks++)
      afr[mt][ks] = *(const half8*)&as16[(mt * 16 + l15) * HP + ks * 32 + quad * 8];

  int c0 = w * 32;
  f32x4 acc[4][2];
#pragma unroll
  for (int mt = 0; mt < 4; mt++)
#pragma unroll
    for (int nt = 0; nt < 2; nt++) acc[mt][nt] = (f32x4){0.f, 0.f, 0.f, 0.f};
#pragma unroll
  for (int ks = 0; ks < 4; ks++) {
    half8 b[2];
#pragma unroll
    for (int nt = 0; nt < 2; nt++)
      b[nt] = *(const half8*)&Woh[(size_t)(c0 + nt * 16 + l15) * 128 + ks * 32 +
                                  quad * 8];
#pragma unroll
    for (int mt = 0; mt < 4; mt++)
#pragma unroll
      for (int nt = 0; nt < 2; nt++)
        acc[mt][nt] =
            __builtin_amdgcn_mfma_f32_16x16x32_f16(afr[mt][ks], b[nt], acc[mt][nt], 0, 0, 0);
  }

#pragma unroll
  for (int nt = 0; nt < 2; nt++) {
    int f = c0 + nt * 16 + l15;
    float bb = bo[f];
    float s = 0.f, q = 0.f;
#pragma unroll
    for (int mt = 0; mt < 4; mt++) {
#pragma unroll
      for (int r = 0; r < 4; r++) {
        int row = mt * 16 + quad * 4 + r;
        float tv = acc[mt][nt][r] + bb + x[(size_t)(base + row) * DIM + f];
        t[(size_t)(base + row) * DIM + f] = tv;
        s += tv;
        q += tv * tv;
      }
    }
    s += __shfl_xor(s, 16);
    s += __shfl_xor(s, 32);
    q += __shfl_xor(q, 16);
    q += __shfl_xor(q, 32);
    if (quad == 0) {
      atomicAdd(&stats[f], s);
      atomicAdd(&stats[128 + f], q);
    }
  }
}

// ------- fused FFN via MFMA; BN1 coef derived per-block from stats ----------
__global__ __launch_bounds__(256) void ffn_mfma(const float* __restrict__ t,
    const float* __restrict__ stats1, const float* __restrict__ g1,
    const float* __restrict__ bb1, const _Float16* __restrict__ W1h,
    const float* __restrict__ b1, const _Float16* __restrict__ W2h,
    const float* __restrict__ b2, float* __restrict__ z,
    float* __restrict__ stats2, float invN, int N) {
  __shared__ _Float16 hs[64 * HP];  // 17.4 KB
  __shared__ _Float16 us[64 * UP];  // 33.8 KB
  __shared__ float cf[256];
  int tid = threadIdx.x;
  int base = blockIdx.x * 64;
  int lane = tid & 63, w = tid >> 6;
  int l15 = lane & 15, quad = lane >> 4;

  if (tid < 128) {
    float mu = stats1[tid] * invN;
    float var = stats1[128 + tid] * invN - mu * mu;
    float a = rsqrtf(var + 1e-5f) * g1[tid];
    cf[tid] = a;
    cf[128 + tid] = bb1[tid] - mu * a;
  }
  __syncthreads();

  for (int i = tid; i < 64 * 32; i += 256) {
    int m = i >> 5, c4 = i & 31;
    float4 tv = ((const float4*)t)[(size_t)(base + m) * 32 + c4];
    float4 ca = ((const float4*)cf)[c4];
    float4 cc = ((const float4*)cf)[32 + c4];
    half4 hv;
    hv.x = (_Float16)(tv.x * ca.x + cc.x);
    hv.y = (_Float16)(tv.y * ca.y + cc.y);
    hv.z = (_Float16)(tv.z * ca.z + cc.z);
    hv.w = (_Float16)(tv.w * ca.w + cc.w);
    *(half4*)&hs[m * HP + c4 * 4] = hv;
  }
  __syncthreads();

  int n0 = w * 64;
  half8 afr[4][4];
#pragma unroll
  for (int mt = 0; mt < 4; mt++)
#pragma unroll
    for (int ks = 0; ks < 4; ks++)
      afr[mt][ks] = *(const half8*)&hs[(mt * 16 + l15) * HP + ks * 32 + quad * 8];

#pragma unroll
  for (int nt = 0; nt < 4; nt++) {
    int n = n0 + nt * 16 + l15;
    half8 bfr[4];
#pragma unroll
    for (int ks = 0; ks < 4; ks++)
      bfr[ks] = *(const half8*)&W1h[(size_t)n * 128 + ks * 32 + quad * 8];
    f32x4 acc[4];
#pragma unroll
    for (int mt = 0; mt < 4; mt++) acc[mt] = (f32x4){0.f, 0.f, 0.f, 0.f};
#pragma unroll
    for (int ks = 0; ks < 4; ks++)
#pragma unroll
      for (int mt = 0; mt < 4; mt++)
        acc[mt] = __builtin_amdgcn_mfma_f32_16x16x32_f16(afr[mt][ks], bfr[ks],
                                                          acc[mt], 0, 0, 0);
    float bias = b1[n];
#pragma unroll
    for (int mt = 0; mt < 4; mt++)
#pragma unroll
      for (int r = 0; r < 4; r++)
        us[(mt * 16 + quad * 4 + r) * UP + n] =
            (_Float16)fmaxf(acc[mt][r] + bias, 0.f);
  }
  __syncthreads();

  int n2 = w * 32;
  f32x4 acc2[4][2];
#pragma unroll
  for (int mt = 0; mt < 4; mt++)
#pragma unroll
    for (int nt = 0; nt < 2; nt++) acc2[mt][nt] = (f32x4){0.f, 0.f, 0.f, 0.f};
  for (int ks = 0; ks < 8; ks++) {
    half8 a[4], b[2];
#pragma unroll
    for (int mt = 0; mt < 4; mt++)
      a[mt] = *(const half8*)&us[(mt * 16 + l15) * UP + ks * 32 + quad * 8];
#pragma unroll
    for (int nt = 0; nt < 2; nt++)
      b[nt] = *(const half8*)&W2h[(size_t)(n2 + nt * 16 + l15) * 256 + ks * 32 +
                                  quad * 8];
#pragma unroll
    for (int mt = 0; mt < 4; mt++)
#pragma unroll
      for (int nt = 0; nt < 2; nt++)
        acc2[mt][nt] =
            __builtin_amdgcn_mfma_f32_16x16x32_f16(a[mt], b[nt], acc2[mt][nt], 0, 0, 0);
  }

#pragma unroll
  for (int nt = 0; nt < 2; nt++) {
    int f = n2 + nt * 16 + l15;
    float bz = b2[f];
    float s = 0.f, q = 0.f;
#pragma unroll
    for (int mt = 0; mt < 4; mt++) {
#pragma unroll
      for (int r = 0; r < 4; r++) {
        int row = mt * 16 + quad * 4 + r;
        float hv = (float)hs[row * HP + f];
        float zv = hv + acc2[mt][nt][r] + bz;
        z[(size_t)(base + row) * DIM + f] = zv;
        s += zv;
        q += zv * zv;
      }
    }
    s += __shfl_xor(s, 16);
    s += __shfl_xor(s, 32);
    q += __shfl_xor(q, 16);
    q += __shfl_xor(q, 32);
    if (quad == 0) {
      atomicAdd(&stats2[f], s);
      atomicAdd(&stats2[128 + f], q);
    }
  }
}

// -------- final BN2 apply; coef derived per-block from stats2 ----------------
__global__ __launch_bounds__(256) void final_apply(const float* __restrict__ z,
    const float* __restrict__ stats2, const float* __restrict__ g2,
    const float* __restrict__ bb2, float* __restrict__ out, float invN,
    int total4) {
  __shared__ float cf[256];
  int tid = threadIdx.x;
  if (tid < 128) {
    float mu = stats2[tid] * invN;
    float var = stats2[128 + tid] * invN - mu * mu;
    float a = rsqrtf(var + 1e-5f) * g2[tid];
    cf[tid] = a;
    cf[128 + tid] = bb2[tid] - mu * a;
  }
  __syncthreads();
  int i = blockIdx.x * 256 + tid;
  if (i >= total4) return;
  int f = (i * 4) & 127;
  float4 zv = ((const float4*)z)[i];
  float4 o;
  o.x = zv.x * cf[f] + cf[128 + f];
  o.y = zv.y * cf[f + 1] + cf[128 + f + 1];
  o.z = zv.z * cf[f + 2] + cf[128 + f + 2];
  o.w = zv.w * cf[f + 3] + cf[128 + f + 3];
  ((float4*)out)[i] = o;
}

extern "C" void kernel_launch(void* const* d_in, const int* in_sizes, int n_in,
                              void* d_out, int out_size, void* d_ws, size_t ws_size,
                              hipStream_t stream) {
  const float* x = (const float*)d_in[0];
  const int* ei = (const int*)d_in[1];
  const float* Wk = (const float*)d_in[2];
  const float* bk = (const float*)d_in[3];
  const float* Wv = (const float*)d_in[4];
  const float* bv = (const float*)d_in[5];
  const float* Wo = (const float*)d_in[6];
  const float* bo = (const float*)d_in[7];
  const float* bn1_g = (const float*)d_in[8];
  const float* bn1_b = (const float*)d_in[9];
  const float* W1 = (const float*)d_in[10];
  const float* b1 = (const float*)d_in[11];
  const float* W2 = (const float*)d_in[12];
  const float* b2 = (const float*)d_in[13];
  const float* bn2_g = (const float*)d_in[14];
  const float* bn2_b = (const float*)d_in[15];
  float* out = (float*)d_out;

  int N = in_sizes[0] / DIM;   // 40000 (= 625 * 64)
  int E = in_sizes[1] / 2;     // 640000

  // workspace layout
  unsigned char* KV8 = (unsigned char*)d_ws;             // 10.25 MB
  _Float16* attn16 = (_Float16*)(KV8 + (size_t)N * 256); // 10.25 MB
  float* zbuf = (float*)(attn16 + (size_t)N * DIM);      // 20.5 MB
  float* tbuf = zbuf + (size_t)N * DIM;                  // 20.5 MB
  _Float16* W1h = (_Float16*)(tbuf + (size_t)N * DIM);
  _Float16* W2h = W1h + 32768;
  _Float16* Wkh = W2h + 32768;
  _Float16* Wvh = Wkh + 16384;
  _Float16* Woh = Wvh + 16384;
  float* stats = (float*)(Woh + 16384);     // 512 floats: stats1 | stats2
  int* cnt = (int*)(stats + 512);           // N * NSHARD
  int* rs = cnt + (size_t)N * NSHARD;       // N+1
  int* rs_shard = rs + N + 1;               // N * NSHARD
  int* rank = rs_shard + (size_t)N * NSHARD;// E
  int* esrc = rank + E;                     // E
  int* bsum = esrc + E;                     // up to 256

  int nblk = (N + 255) / 256;
  float invN = 1.0f / N;

  conv_wall<<<512, 256, 0, stream>>>(Wk, Wv, Wo, W1, W2, Wkh, Wvh, Woh, W1h, W2h,
                                     cnt, stats, N);
  kv_mfma<<<N / 64, 256, 0, stream>>>(x, Wkh, bk, Wvh, bv, KV8, N);
  hist_rank<<<(E + 255) / 256, 256, 0, stream>>>(ei, cnt, rank, N, E);
  scanA<<<nblk, 256, 0, stream>>>(cnt, rs, bsum, N);
  scanB<<<1, 256, 0, stream>>>(bsum, nblk);
  scanC<<<nblk, 256, 0, stream>>>(rs, bsum, cnt, rs_shard, N, E);
  scatter2<<<(E + 255) / 256, 256, 0, stream>>>(ei, rs_shard, rank, esrc, N, E);
  attn_agg<<<(N + 3) / 4, 256, 0, stream>>>(KV8, x, rs, esrc, attn16, N);
  o_proj_mfma<<<N / 64, 256, 0, stream>>>(attn16, x, Woh, bo, tbuf, stats, N);
  ffn_mfma<<<N / 64, 256, 0, stream>>>(tbuf, stats, bn1_g, bn1_b, W1h, b1, W2h, b2,
                                       zbuf, stats + 256, invN, N);
  final_apply<<<((N * DIM / 4) + 255) / 256, 256, 0, stream>>>(
      zbuf, stats + 256, bn2_g, bn2_b, out, invN, N * DIM / 4);
}